// Round 4
// baseline (516.076 us; speedup 1.0000x reference)
//
#include <hip/hip_runtime.h>
#include <math.h>

// Router: logits = x@Wg ; softmax ; top-2 ; renormalized combine.
// T=65536, D=1024, E=64. Out flat fp32: [combine 2T][idx-as-float 2T][probs 64T].
//
// R4 = R3 minus the float4->float* type-punning (it forced wf[] into scratch:
// R3 showed 362 MB WRITE_SIZE vs 17.8 MB of actual output). All fragment
// accesses are explicit components now. Accumulation order (d ascending per
// expert) is unchanged -> numerics identical to the passing R3.

#define D_DIM 1024
#define E_DIM 64
#define TPB   128
#define TOK   64        // tokens per block
#define DC    32        // d-rows per chunk
#define NCH   (D_DIM / DC)
#define XS    36        // x tile stride (floats); 144 B = 9*16 -> b128-aligned
#define WSd   64        // w tile stride
#define LS    65        // logits tile stride

__global__ __launch_bounds__(TPB, 2) void router_kernel(
    const float* __restrict__ x, const float* __restrict__ Wg,
    float* __restrict__ out, int T)
{
    __shared__ float sx[2][TOK * XS];   // 18432 B
    __shared__ float sw[2][DC * WSd];   // 16384 B   (total 34816 B -> 4 blocks/CU)

    const int tid  = threadIdx.x;
    const int lane = tid & 63;
    const int wv   = __builtin_amdgcn_readfirstlane(tid >> 6);  // wave: experts 0-31 / 32-63
    const int tr   = lane >> 3;          // token row: lane's tokens are tr + 8i
    const int ec   = lane & 7;           // expert col
    const int we   = wv * 32 + (ec << 2);
    const int base = blockIdx.x * TOK;

    float acc[8][4];
#pragma unroll
    for (int i = 0; i < 8; ++i)
#pragma unroll
        for (int j = 0; j < 4; ++j) acc[i][j] = 0.0f;

    // staging maps: x chunk = 64 tok x 32 d = 512 float4; w chunk = 32 d x 64 e = 512 float4
    int xt[4], xc[4], wr_[4], wc[4];
#pragma unroll
    for (int p = 0; p < 4; ++p) {
        const int vid = tid + p * TPB;
        xt[p]  = vid >> 3;          // 0..63
        xc[p]  = (vid & 7) << 2;    // 0..28
        wr_[p] = vid >> 4;          // 0..31
        wc[p]  = (vid & 15) << 2;   // 0..60
    }

    float4 xst[4], wst[4];

#define LOAD_CHUNK(dc)                                                              \
    {                                                                               \
        _Pragma("unroll")                                                           \
        for (int p = 0; p < 4; ++p)                                                 \
            xst[p] = *(const float4*)&x[(size_t)(base + xt[p]) * D_DIM + (dc) + xc[p]]; \
        _Pragma("unroll")                                                           \
        for (int p = 0; p < 4; ++p)                                                 \
            wst[p] = *(const float4*)&Wg[(size_t)((dc) + wr_[p]) * E_DIM + wc[p]];  \
    }

#define WRITE_CHUNK(b)                                                              \
    {                                                                               \
        _Pragma("unroll")                                                           \
        for (int p = 0; p < 4; ++p) *(float4*)&sx[b][xt[p] * XS + xc[p]] = xst[p];  \
        _Pragma("unroll")                                                           \
        for (int p = 0; p < 4; ++p) *(float4*)&sw[b][wr_[p] * WSd + wc[p]] = wst[p];\
    }

    LOAD_CHUNK(0)
    WRITE_CHUNK(0)
    LOAD_CHUNK(DC)
    __syncthreads();

    for (int ch = 0; ch < NCH; ++ch) {
        const int cur = ch & 1;
        if (ch + 1 < NCH) WRITE_CHUNK(ch & 1 ? 0 : 1)        // chunk ch+1 regs -> other buffer
        if (ch + 2 < NCH) LOAD_CHUNK((ch + 2) * DC)          // prefetch 2 ahead

        const float* __restrict__ bx = sx[cur];
        const float* __restrict__ bw = sw[cur];

#pragma unroll 2
        for (int g = 0; g < DC; g += 4) {
            float4 xf[8];
            float4 wf0, wf1, wf2, wf3;
#pragma unroll
            for (int i = 0; i < 8; ++i)
                xf[i] = *(const float4*)&bx[(tr + 8 * i) * XS + g];     // broadcast x8 over ec
            wf0 = *(const float4*)&bw[(g + 0) * WSd + we];              // broadcast x8 over tr
            wf1 = *(const float4*)&bw[(g + 1) * WSd + we];
            wf2 = *(const float4*)&bw[(g + 2) * WSd + we];
            wf3 = *(const float4*)&bw[(g + 3) * WSd + we];
#pragma unroll
            for (int i = 0; i < 8; ++i) {
                const float4 xv = xf[i];
                float a0 = acc[i][0], a1 = acc[i][1], a2 = acc[i][2], a3 = acc[i][3];
                // d ascending per accumulator: numerics identical to R3/R2
                a0 = fmaf(xv.x, wf0.x, a0); a0 = fmaf(xv.y, wf1.x, a0);
                a0 = fmaf(xv.z, wf2.x, a0); a0 = fmaf(xv.w, wf3.x, a0);
                a1 = fmaf(xv.x, wf0.y, a1); a1 = fmaf(xv.y, wf1.y, a1);
                a1 = fmaf(xv.z, wf2.y, a1); a1 = fmaf(xv.w, wf3.y, a1);
                a2 = fmaf(xv.x, wf0.z, a2); a2 = fmaf(xv.y, wf1.z, a2);
                a2 = fmaf(xv.z, wf2.z, a2); a2 = fmaf(xv.w, wf3.z, a2);
                a3 = fmaf(xv.x, wf0.w, a3); a3 = fmaf(xv.y, wf1.w, a3);
                a3 = fmaf(xv.z, wf2.w, a3); a3 = fmaf(xv.w, wf3.w, a3);
                acc[i][0] = a0; acc[i][1] = a1; acc[i][2] = a2; acc[i][3] = a3;
            }
        }
        __syncthreads();
    }

    // ---- logits -> LDS (overlay on sx: 4608 floats >= 64*65) ----
    float* sl = &sx[0][0];
#pragma unroll
    for (int i = 0; i < 8; ++i) {
        sl[(tr + 8 * i) * LS + we + 0] = acc[i][0];
        sl[(tr + 8 * i) * LS + we + 1] = acc[i][1];
        sl[(tr + 8 * i) * LS + we + 2] = acc[i][2];
        sl[(tr + 8 * i) * LS + we + 3] = acc[i][3];
    }
    __syncthreads();

    // ---- epilogue: wave 0, one thread per token ----
    if (tid < TOK) {
        const int t = tid;
        float m = -INFINITY;
#pragma unroll
        for (int e = 0; e < E_DIM; ++e) m = fmaxf(m, sl[t * LS + e]);

        float s = 0.0f;
#pragma unroll
        for (int e = 0; e < E_DIM; ++e) {
            const float p = expf(sl[t * LS + e] - m);
            sl[t * LS + e] = p;
            s += p;
        }
        const float inv = 1.0f / s;

        float v1 = -1.0f, v2 = -1.0f;
        int   i1 = 0,     i2 = 0;
#pragma unroll
        for (int e = 0; e < E_DIM; ++e) {
            const float p = sl[t * LS + e] * inv;
            sl[t * LS + e] = p;
            if (p > v1)      { v2 = v1; i2 = i1; v1 = p; i1 = e; }
            else if (p > v2) { v2 = p;  i2 = e; }
        }

        const float denom = v1 + v2;
        const int token = base + t;
        *(float2*)&out[(size_t)2 * token]                 = make_float2(v1 / denom, v2 / denom);
        *(float2*)&out[(size_t)2 * T + (size_t)2 * token] = make_float2((float)i1, (float)i2);
    }
    __syncthreads();

    // ---- coalesced probs write: 16 KB block region, linear float4 ----
    float* __restrict__ po = out + (size_t)4 * T + (size_t)base * E_DIM;
#pragma unroll
    for (int k = 0; k < 8; ++k) {
        const int g = (tid + k * TPB) << 2;
        const int t = g >> 6;
        const int e = g & 63;
        *(float4*)&po[g] = make_float4(sl[t * LS + e],     sl[t * LS + e + 1],
                                       sl[t * LS + e + 2], sl[t * LS + e + 3]);
    }
}

extern "C" void kernel_launch(void* const* d_in, const int* in_sizes, int n_in,
                              void* d_out, int out_size, void* d_ws, size_t ws_size,
                              hipStream_t stream) {
    const float* x  = (const float*)d_in[0];
    const float* Wg = (const float*)d_in[1];
    float* out = (float*)d_out;
    const int T = in_sizes[0] / D_DIM;   // 65536

    router_kernel<<<dim3(T / TOK), dim3(TPB), 0, stream>>>(x, Wg, out, T);
}